// Round 1
// baseline (626.817 us; speedup 1.0000x reference)
//
#include <hip/hip_runtime.h>

#define IN_F 4096
#define OUT_F 4096
#define M_ROWS 8192
#define GK 4096

typedef float  floatx4 __attribute__((ext_vector_type(4)));
typedef short  shortx8 __attribute__((ext_vector_type(8)));

__device__ __forceinline__ unsigned short f2bf(float f) {
    // round-to-nearest-even fp32 -> bf16
    unsigned int u = __float_as_uint(f);
    u = (u + 0x7FFFu + ((u >> 16) & 1u)) >> 16;
    return (unsigned short)u;
}

__constant__ float NF4_TAB[16] = {
    -1.0f, -0.6961928009986877f, -0.5250730514526367f, -0.39491748809814453f,
    -0.28444138169288635f, -0.18477343022823334f, -0.09105003625154495f, 0.0f,
    0.07958029955625534f, 0.16093020141124725f, 0.2461123913526535f, 0.33791524171829224f,
    0.44070982933044434f, 0.5626170039176941f, 0.7229568362236023f, 1.0f
};

// ---------------------------------------------------------------------------
// Kernel 1: W_eff[o][i] = nf4[nibble] * absmax + sum_r B[o][r]*A[r][i]  (bf16)
// Tile: 128 o-rows x 128 i-cols per block; B-tile transposed into LDS,
// A read through L1 (tile fits in 32 KiB L1 and is reused across o-blocks).
// ---------------------------------------------------------------------------
__global__ __launch_bounds__(256) void build_weff(
    const int*   __restrict__ qw,
    const float* __restrict__ absmax,
    const float* __restrict__ A,     // (64, IN_F) row-major
    const float* __restrict__ Bm,    // (OUT_F, 64) row-major
    short*       __restrict__ W)     // (OUT_F, IN_F) bf16 bits
{
    __shared__ float Bsh[64][128];   // Bsh[r][o_local]
    __shared__ float nf4s[16];

    const int t  = threadIdx.x;
    const int ib = blockIdx.x * 128;
    const int ob = blockIdx.y * 128;

    if (t < 16) nf4s[t] = NF4_TAB[t];

    // load + transpose B tile: 128 o x 64 r = 8192 floats
    #pragma unroll
    for (int it = 0; it < 8; ++it) {
        int idx = t * 4 + it * 1024;
        int o  = idx >> 6;
        int r0 = idx & 63;
        float4 bb = *(const float4*)(Bm + (size_t)(ob + o) * 64 + r0);
        Bsh[r0 + 0][o] = bb.x;
        Bsh[r0 + 1][o] = bb.y;
        Bsh[r0 + 2][o] = bb.z;
        Bsh[r0 + 3][o] = bb.w;
    }
    __syncthreads();

    const int o0 = (t >> 4) * 8;   // 8 output rows per thread
    const int i0 = (t & 15) * 8;   // 8 cols per thread

    float acc[8][8];
    #pragma unroll
    for (int a = 0; a < 8; ++a)
        #pragma unroll
        for (int b = 0; b < 8; ++b) acc[a][b] = 0.f;

    const float* Ap = A + ib + i0;
    for (int r = 0; r < 64; ++r) {
        float4 a0 = *(const float4*)(Ap);
        float4 a1 = *(const float4*)(Ap + 4);
        Ap += IN_F;
        float av[8] = {a0.x, a0.y, a0.z, a0.w, a1.x, a1.y, a1.z, a1.w};
        #pragma unroll
        for (int a = 0; a < 8; ++a) {
            float bv = Bsh[r][o0 + a];
            #pragma unroll
            for (int b = 0; b < 8; ++b)
                acc[a][b] = fmaf(bv, av[b], acc[a][b]);
        }
    }

    // dequant + add lora + store (8 rows x 8 cols, 16B store per row)
    #pragma unroll
    for (int a = 0; a < 8; ++a) {
        const int    o  = ob + o0 + a;
        const size_t fb = (size_t)o * IN_F + (ib + i0);   // flat weight index
        const int4  q   = *(const int4*)(qw + (fb >> 1)); // 4 ints -> 8 nibbles
        const float am  = absmax[fb >> 6];
        union { unsigned short u[8]; int4 v; } pk;
        const int qs[4] = {q.x, q.y, q.z, q.w};
        #pragma unroll
        for (int p = 0; p < 4; ++p) {
            pk.u[2*p]   = f2bf(fmaf(nf4s[qs[p] & 15],        am, acc[a][2*p]));
            pk.u[2*p+1] = f2bf(fmaf(nf4s[(qs[p] >> 4) & 15], am, acc[a][2*p+1]));
        }
        *(int4*)(W + fb) = pk.v;
    }
}

// ---------------------------------------------------------------------------
// Kernel 2: cast x (fp32) -> bf16, 8 elems/thread, 16B store
// ---------------------------------------------------------------------------
__global__ __launch_bounds__(256) void cast_x(
    const float* __restrict__ x, short* __restrict__ xb)
{
    const size_t i = ((size_t)blockIdx.x * 256 + threadIdx.x) * 8;
    float4 a = *(const float4*)(x + i);
    float4 b = *(const float4*)(x + i + 4);
    union { unsigned short u[8]; int4 v; } p;
    p.u[0] = f2bf(a.x); p.u[1] = f2bf(a.y); p.u[2] = f2bf(a.z); p.u[3] = f2bf(a.w);
    p.u[4] = f2bf(b.x); p.u[5] = f2bf(b.y); p.u[6] = f2bf(b.z); p.u[7] = f2bf(b.w);
    *(int4*)(xb + i) = p.v;
}

// ---------------------------------------------------------------------------
// Kernel 3: C[M][N] = Xb[M][K] * Wb[N][K]^T  (m97-style 128x128x32 MFMA GEMM)
// ---------------------------------------------------------------------------
#define BM 128
#define BN 128
#define BK 32

__device__ __forceinline__ void gll16(const void* g, void* l) {
    __builtin_amdgcn_global_load_lds(
        (const __attribute__((address_space(1))) void*)g,
        (__attribute__((address_space(3))) void*)l, 16, 0, 0);
}

__global__ __launch_bounds__(256) void gemm_bt(
    const short* __restrict__ Xb,   // M x K bf16
    const short* __restrict__ Wb,   // N x K bf16
    float*       __restrict__ C)    // M x N fp32
{
    __shared__ short As[BM * BK];
    __shared__ short Bs[BN * BK];

    const int tid  = threadIdx.x;
    const int lane = tid & 63;
    const int wave = tid >> 6;
    const int bn = blockIdx.x * BN;
    const int bm = blockIdx.y * BM;

    // staging: thread t -> LDS bytes [t*16, t*16+16) and +4096; global matches
    const int ar = tid >> 2;
    const int ac = (tid & 3) * 8;
    const short* gA0 = Xb + (size_t)(bm + ar) * GK + ac;
    const short* gA1 = gA0 + (size_t)64 * GK;
    const short* gB0 = Wb + (size_t)(bn + ar) * GK + ac;
    const short* gB1 = gB0 + (size_t)64 * GK;
    short* lA0 = As + tid * 8;
    short* lA1 = As + 2048 + tid * 8;
    short* lB0 = Bs + tid * 8;
    short* lB1 = Bs + 2048 + tid * 8;

    const int wm = (wave >> 1) * 64;   // wave's 64x64 quadrant
    const int wn = (wave & 1) * 64;
    const int fr = lane & 15;          // fragment row (m or n)
    const int fk = (lane >> 4) * 8;    // fragment k offset

    floatx4 zero = {0.f, 0.f, 0.f, 0.f};
    floatx4 acc[4][4];
    #pragma unroll
    for (int i = 0; i < 4; ++i)
        #pragma unroll
        for (int j = 0; j < 4; ++j) acc[i][j] = zero;

    for (int kt = 0; kt < GK / BK; ++kt) {
        gll16(gA0, lA0);
        gll16(gA1, lA1);
        gll16(gB0, lB0);
        gll16(gB1, lB1);
        gA0 += BK; gA1 += BK; gB0 += BK; gB1 += BK;
        __syncthreads();   // vmcnt(0) drain + barrier: LDS data ready

        shortx8 af[4], bfr[4];
        #pragma unroll
        for (int i = 0; i < 4; ++i) {
            af[i]  = *(const shortx8*)&As[(wm + i * 16 + fr) * BK + fk];
            bfr[i] = *(const shortx8*)&Bs[(wn + i * 16 + fr) * BK + fk];
        }
        #pragma unroll
        for (int i = 0; i < 4; ++i)
            #pragma unroll
            for (int j = 0; j < 4; ++j)
                acc[i][j] = __builtin_amdgcn_mfma_f32_16x16x32_bf16(
                    af[i], bfr[j], acc[i][j], 0, 0, 0);
        __syncthreads();   // protect LDS before next stage
    }

    // epilogue: C/D layout col=lane&15, row=(lane>>4)*4+reg  [m89/m91 verified]
    const int row0 = bm + wm + (lane >> 4) * 4;
    const int col0 = bn + wn + fr;
    #pragma unroll
    for (int i = 0; i < 4; ++i)
        #pragma unroll
        for (int j = 0; j < 4; ++j) {
            float* cp = C + (size_t)(row0 + i * 16) * OUT_F + col0 + j * 16;
            #pragma unroll
            for (int rr = 0; rr < 4; ++rr)
                cp[(size_t)rr * OUT_F] = acc[i][j][rr];
        }
}

// ---------------------------------------------------------------------------
extern "C" void kernel_launch(void* const* d_in, const int* in_sizes, int n_in,
                              void* d_out, int out_size, void* d_ws, size_t ws_size,
                              hipStream_t stream) {
    const float* x  = (const float*)d_in[0];
    const int*   qw = (const int*)d_in[1];
    const float* am = (const float*)d_in[2];
    const float* lA = (const float*)d_in[3];
    const float* lB = (const float*)d_in[4];
    float* out = (float*)d_out;

    short* Weff = (short*)d_ws;                                   // 4096*4096 bf16 = 32 MiB
    short* Xb   = (short*)((char*)d_ws + (size_t)OUT_F * IN_F * 2); // 8192*4096 bf16 = 64 MiB

    build_weff<<<dim3(IN_F / 128, OUT_F / 128), 256, 0, stream>>>(qw, am, lA, lB, Weff);
    cast_x<<<(M_ROWS * IN_F) / (256 * 8), 256, 0, stream>>>(x, Xb);
    gemm_bt<<<dim3(OUT_F / BN, M_ROWS / BM), 256, 0, stream>>>(Xb, Weff, out);
}

// Round 2
// 598.376 us; speedup vs baseline: 1.0475x; 1.0475x over previous
//
#include <hip/hip_runtime.h>

#define IN_F 4096
#define OUT_F 4096
#define M_ROWS 8192
#define GK 4096

typedef float  floatx4 __attribute__((ext_vector_type(4)));
typedef short  shortx8 __attribute__((ext_vector_type(8)));

__device__ __forceinline__ unsigned short f2bf(float f) {
    unsigned int u = __float_as_uint(f);
    u = (u + 0x7FFFu + ((u >> 16) & 1u)) >> 16;
    return (unsigned short)u;
}

__constant__ float NF4_TAB[16] = {
    -1.0f, -0.6961928009986877f, -0.5250730514526367f, -0.39491748809814453f,
    -0.28444138169288635f, -0.18477343022823334f, -0.09105003625154495f, 0.0f,
    0.07958029955625534f, 0.16093020141124725f, 0.2461123913526535f, 0.33791524171829224f,
    0.44070982933044434f, 0.5626170039176941f, 0.7229568362236023f, 1.0f
};

__device__ __forceinline__ void gll16(const void* g, void* l) {
    __builtin_amdgcn_global_load_lds(
        (const __attribute__((address_space(1))) void*)g,
        (__attribute__((address_space(3))) void*)l, 16, 0, 0);
}

// ---------------------------------------------------------------------------
// cast_x: fp32 -> bf16, 8 elems/thread
// ---------------------------------------------------------------------------
__global__ __launch_bounds__(256) void cast_x(
    const float* __restrict__ x, short* __restrict__ xb)
{
    const size_t i = ((size_t)blockIdx.x * 256 + threadIdx.x) * 8;
    float4 a = *(const float4*)(x + i);
    float4 b = *(const float4*)(x + i + 4);
    union { unsigned short u[8]; int4 v; } p;
    p.u[0] = f2bf(a.x); p.u[1] = f2bf(a.y); p.u[2] = f2bf(a.z); p.u[3] = f2bf(a.w);
    p.u[4] = f2bf(b.x); p.u[5] = f2bf(b.y); p.u[6] = f2bf(b.z); p.u[7] = f2bf(b.w);
    *(int4*)(xb + i) = p.v;
}

// cast_B: lora_B (OUT_F x 64 fp32) -> bf16 same layout
__global__ __launch_bounds__(256) void cast_B(
    const float* __restrict__ Bm, short* __restrict__ Bb)
{
    const size_t i = ((size_t)blockIdx.x * 256 + threadIdx.x) * 8;
    float4 a = *(const float4*)(Bm + i);
    float4 b = *(const float4*)(Bm + i + 4);
    union { unsigned short u[8]; int4 v; } p;
    p.u[0] = f2bf(a.x); p.u[1] = f2bf(a.y); p.u[2] = f2bf(a.z); p.u[3] = f2bf(a.w);
    p.u[4] = f2bf(b.x); p.u[5] = f2bf(b.y); p.u[6] = f2bf(b.z); p.u[7] = f2bf(b.w);
    *(int4*)(Bb + i) = p.v;
}

// cast_At: lora_A (64 x IN_F fp32) -> At (IN_F x 64 bf16), transposed via LDS
__global__ __launch_bounds__(256) void cast_At(
    const float* __restrict__ A, short* __restrict__ At)
{
    __shared__ float tile[64][65];
    const int ib = blockIdx.x * 64;
    const int t  = threadIdx.x;
    {
        const int r = t >> 2, c0 = (t & 3) * 16;
        #pragma unroll
        for (int k = 0; k < 4; ++k) {
            float4 v = *(const float4*)(A + (size_t)r * IN_F + ib + c0 + k * 4);
            tile[r][c0 + k * 4 + 0] = v.x;
            tile[r][c0 + k * 4 + 1] = v.y;
            tile[r][c0 + k * 4 + 2] = v.z;
            tile[r][c0 + k * 4 + 3] = v.w;
        }
    }
    __syncthreads();
    const int i = t >> 2, r0 = (t & 3) * 16;
    union { unsigned short u[8]; int4 v; } p0, p1;
    #pragma unroll
    for (int k = 0; k < 8; ++k) p0.u[k] = f2bf(tile[r0 + k][i]);
    #pragma unroll
    for (int k = 0; k < 8; ++k) p1.u[k] = f2bf(tile[r0 + 8 + k][i]);
    *(int4*)(At + (size_t)(ib + i) * 64 + r0)     = p0.v;
    *(int4*)(At + (size_t)(ib + i) * 64 + r0 + 8) = p1.v;
}

// ---------------------------------------------------------------------------
// lora_weff: Weff[o][i] = nf4[nib]*absmax + sum_r B[o][r]*A[r][i]   (bf16 out)
// MFMA GEMM over K=64: Xside = Bb (OUT_F x 64), Wside = At (IN_F x 64).
// Same 128x128 swizzled structure as main gemm; dequant fused in epilogue.
// ---------------------------------------------------------------------------
#define BM 128
#define BN 128
#define BK 32

__global__ __launch_bounds__(256) void lora_weff(
    const short* __restrict__ Bb,      // OUT_F x 64 bf16
    const short* __restrict__ At,      // IN_F x 64 bf16
    const int*   __restrict__ qw,      // one byte-value per int32, 2 nibbles
    const float* __restrict__ absmax,
    short*       __restrict__ W)       // OUT_F x IN_F bf16
{
    __shared__ short As[BM * BK];
    __shared__ short Bs[BN * BK];
    __shared__ float nf4s[16];

    const int tid  = threadIdx.x;
    const int lane = tid & 63;
    const int wave = tid >> 6;
    const int bn = blockIdx.x * BN;   // i dim
    const int bm = blockIdx.y * BM;   // o dim

    if (tid < 16) nf4s[tid] = NF4_TAB[tid];

    // staging with XOR swizzle: thread t -> LDS row ar, chunk-pos c; loads
    // global chunk c ^ ((ar>>1)&3)
    const int ar = tid >> 2;
    const int ac = ((tid & 3) ^ ((ar >> 1) & 3)) * 8;
    const short* gA0 = Bb + (size_t)(bm + ar) * 64 + ac;
    const short* gA1 = gA0 + (size_t)64 * 64;
    const short* gB0 = At + (size_t)(bn + ar) * 64 + ac;
    const short* gB1 = gB0 + (size_t)64 * 64;
    short* lA0 = As + tid * 8;
    short* lA1 = As + 2048 + tid * 8;
    short* lB0 = Bs + tid * 8;
    short* lB1 = Bs + 2048 + tid * 8;

    const int wm = (wave >> 1) * 64;
    const int wn = (wave & 1) * 64;
    const int fr = lane & 15;
    const int fk_sw = (((lane >> 4) ^ ((fr >> 1) & 3))) * 8;   // swizzled chunk

    floatx4 zero = {0.f, 0.f, 0.f, 0.f};
    floatx4 acc[4][4];
    #pragma unroll
    for (int i = 0; i < 4; ++i)
        #pragma unroll
        for (int j = 0; j < 4; ++j) acc[i][j] = zero;

    #pragma unroll
    for (int kt = 0; kt < 2; ++kt) {
        gll16(gA0, lA0);
        gll16(gA1, lA1);
        gll16(gB0, lB0);
        gll16(gB1, lB1);
        gA0 += BK; gA1 += BK; gB0 += BK; gB1 += BK;
        __syncthreads();

        shortx8 af[4], bfr[4];
        #pragma unroll
        for (int i = 0; i < 4; ++i) {
            af[i]  = *(const shortx8*)&As[(wm + i * 16 + fr) * BK + fk_sw];
            bfr[i] = *(const shortx8*)&Bs[(wn + i * 16 + fr) * BK + fk_sw];
        }
        #pragma unroll
        for (int i = 0; i < 4; ++i)
            #pragma unroll
            for (int j = 0; j < 4; ++j)
                acc[i][j] = __builtin_amdgcn_mfma_f32_16x16x32_bf16(
                    af[i], bfr[j], acc[i][j], 0, 0, 0);
        __syncthreads();
    }

    // epilogue: element (o, ic); dequant + add lora, store bf16
    const int row0 = bm + wm + (lane >> 4) * 4;
    const int col0 = bn + wn + fr;
    const int amcol = (bn + wn) >> 6;   // absmax col-block, constant per row
    #pragma unroll
    for (int i = 0; i < 4; ++i) {
        #pragma unroll
        for (int rr = 0; rr < 4; ++rr) {
            const int o = row0 + i * 16 + rr;
            const float am = absmax[(size_t)o * 64 + amcol];
            #pragma unroll
            for (int j = 0; j < 4; ++j) {
                const int ic = col0 + j * 16;
                const size_t flat = (size_t)o * IN_F + ic;
                const int q = qw[flat >> 1];
                const int nib = (ic & 1) ? ((q >> 4) & 15) : (q & 15);
                W[flat] = f2bf(fmaf(nf4s[nib], am, acc[i][j][rr]));
            }
        }
    }
}

// ---------------------------------------------------------------------------
// gemm_bt: C[M][N] = Xb[M][K] * Wb[N][K]^T   (128x128x32, XOR-swizzled LDS)
// ---------------------------------------------------------------------------
__global__ __launch_bounds__(256) void gemm_bt(
    const short* __restrict__ Xb,   // M x K bf16
    const short* __restrict__ Wb,   // N x K bf16
    float*       __restrict__ C)    // M x N fp32
{
    __shared__ short As[BM * BK];
    __shared__ short Bs[BN * BK];

    const int tid  = threadIdx.x;
    const int lane = tid & 63;
    const int wave = tid >> 6;
    const int bn = blockIdx.x * BN;
    const int bm = blockIdx.y * BM;

    // staging with XOR swizzle (see lora_weff)
    const int ar = tid >> 2;
    const int ac = ((tid & 3) ^ ((ar >> 1) & 3)) * 8;
    const short* gA0 = Xb + (size_t)(bm + ar) * GK + ac;
    const short* gA1 = gA0 + (size_t)64 * GK;
    const short* gB0 = Wb + (size_t)(bn + ar) * GK + ac;
    const short* gB1 = gB0 + (size_t)64 * GK;
    short* lA0 = As + tid * 8;
    short* lA1 = As + 2048 + tid * 8;
    short* lB0 = Bs + tid * 8;
    short* lB1 = Bs + 2048 + tid * 8;

    const int wm = (wave >> 1) * 64;
    const int wn = (wave & 1) * 64;
    const int fr = lane & 15;
    const int fk_sw = (((lane >> 4) ^ ((fr >> 1) & 3))) * 8;

    floatx4 zero = {0.f, 0.f, 0.f, 0.f};
    floatx4 acc[4][4];
    #pragma unroll
    for (int i = 0; i < 4; ++i)
        #pragma unroll
        for (int j = 0; j < 4; ++j) acc[i][j] = zero;

    for (int kt = 0; kt < GK / BK; ++kt) {
        gll16(gA0, lA0);
        gll16(gA1, lA1);
        gll16(gB0, lB0);
        gll16(gB1, lB1);
        gA0 += BK; gA1 += BK; gB0 += BK; gB1 += BK;
        __syncthreads();

        shortx8 af[4], bfr[4];
        #pragma unroll
        for (int i = 0; i < 4; ++i) {
            af[i]  = *(const shortx8*)&As[(wm + i * 16 + fr) * BK + fk_sw];
            bfr[i] = *(const shortx8*)&Bs[(wn + i * 16 + fr) * BK + fk_sw];
        }
        #pragma unroll
        for (int i = 0; i < 4; ++i)
            #pragma unroll
            for (int j = 0; j < 4; ++j)
                acc[i][j] = __builtin_amdgcn_mfma_f32_16x16x32_bf16(
                    af[i], bfr[j], acc[i][j], 0, 0, 0);
        __syncthreads();
    }

    // epilogue: C/D layout col=lane&15, row=(lane>>4)*4+reg
    const int row0 = bm + wm + (lane >> 4) * 4;
    const int col0 = bn + wn + fr;
    #pragma unroll
    for (int i = 0; i < 4; ++i)
        #pragma unroll
        for (int j = 0; j < 4; ++j) {
            float* cp = C + (size_t)(row0 + i * 16) * OUT_F + col0 + j * 16;
            #pragma unroll
            for (int rr = 0; rr < 4; ++rr)
                cp[(size_t)rr * OUT_F] = acc[i][j][rr];
        }
}

// ---------------------------------------------------------------------------
extern "C" void kernel_launch(void* const* d_in, const int* in_sizes, int n_in,
                              void* d_out, int out_size, void* d_ws, size_t ws_size,
                              hipStream_t stream) {
    const float* x  = (const float*)d_in[0];
    const int*   qw = (const int*)d_in[1];
    const float* am = (const float*)d_in[2];
    const float* lA = (const float*)d_in[3];
    const float* lB = (const float*)d_in[4];
    float* out = (float*)d_out;

    short* Weff = (short*)d_ws;                                     // 32 MiB
    short* Xb   = (short*)((char*)d_ws + (size_t)OUT_F * IN_F * 2); // 64 MiB
    // At/Bb live inside the Xb region; lora_weff completes before cast_x
    // overwrites them (stream-ordered).
    short* At   = Xb;                     // IN_F x 64 bf16 = 512 KiB
    short* Bb   = Xb + (size_t)IN_F * 64; // OUT_F x 64 bf16 = 512 KiB

    cast_At<<<IN_F / 64, 256, 0, stream>>>(lA, At);
    cast_B<<<(OUT_F * 64) / (256 * 8), 256, 0, stream>>>(lB, Bb);
    lora_weff<<<dim3(IN_F / 128, OUT_F / 128), 256, 0, stream>>>(Bb, At, qw, am, Weff);
    cast_x<<<(M_ROWS * IN_F) / (256 * 8), 256, 0, stream>>>(x, Xb);
    gemm_bt<<<dim3(OUT_F / BN, M_ROWS / BM), 256, 0, stream>>>(Xb, Weff, out);
}

// Round 3
// 546.989 us; speedup vs baseline: 1.1459x; 1.0939x over previous
//
#include <hip/hip_runtime.h>

#define IN_F 4096
#define OUT_F 4096
#define M_ROWS 8192
#define GK 4096

typedef float  floatx4 __attribute__((ext_vector_type(4)));
typedef short  shortx8 __attribute__((ext_vector_type(8)));

__device__ __forceinline__ unsigned short f2bf(float f) {
    unsigned int u = __float_as_uint(f);
    u = (u + 0x7FFFu + ((u >> 16) & 1u)) >> 16;
    return (unsigned short)u;
}

__constant__ float NF4_TAB[16] = {
    -1.0f, -0.6961928009986877f, -0.5250730514526367f, -0.39491748809814453f,
    -0.28444138169288635f, -0.18477343022823334f, -0.09105003625154495f, 0.0f,
    0.07958029955625534f, 0.16093020141124725f, 0.2461123913526535f, 0.33791524171829224f,
    0.44070982933044434f, 0.5626170039176941f, 0.7229568362236023f, 1.0f
};

__device__ __forceinline__ void gll16(const void* g, void* l) {
    __builtin_amdgcn_global_load_lds(
        (const __attribute__((address_space(1))) void*)g,
        (__attribute__((address_space(3))) void*)l, 16, 0, 0);
}

// ---------------------------------------------------------------------------
// prep: one launch for all three casts.
//   blocks [0,64)        : lora_A (64 x IN_F fp32) -> At (IN_F x 64 bf16)
//   blocks [64,192)      : lora_B (OUT_F x 64 fp32) -> Bb bf16 (same layout)
//   blocks [192,192+16384): x fp32 -> Xb bf16
// ---------------------------------------------------------------------------
__global__ __launch_bounds__(256) void prep(
    const float* __restrict__ A, const float* __restrict__ Bm,
    const float* __restrict__ x,
    short* __restrict__ At, short* __restrict__ Bb, short* __restrict__ Xb)
{
    __shared__ float tile[64][65];
    const int b = blockIdx.x;
    const int t = threadIdx.x;

    if (b < 64) {
        // transpose-cast lora_A
        const int ib = b * 64;
        const int r = t >> 2, c0 = (t & 3) * 16;
        #pragma unroll
        for (int k = 0; k < 4; ++k) {
            float4 v = *(const float4*)(A + (size_t)r * IN_F + ib + c0 + k * 4);
            tile[r][c0 + k * 4 + 0] = v.x;
            tile[r][c0 + k * 4 + 1] = v.y;
            tile[r][c0 + k * 4 + 2] = v.z;
            tile[r][c0 + k * 4 + 3] = v.w;
        }
        __syncthreads();
        const int i = t >> 2, r0 = (t & 3) * 16;
        union { unsigned short u[8]; int4 v; } p0, p1;
        #pragma unroll
        for (int k = 0; k < 8; ++k) p0.u[k] = f2bf(tile[r0 + k][i]);
        #pragma unroll
        for (int k = 0; k < 8; ++k) p1.u[k] = f2bf(tile[r0 + 8 + k][i]);
        *(int4*)(At + (size_t)(ib + i) * 64 + r0)     = p0.v;
        *(int4*)(At + (size_t)(ib + i) * 64 + r0 + 8) = p1.v;
    } else if (b < 192) {
        const size_t i = ((size_t)(b - 64) * 256 + t) * 8;
        float4 a = *(const float4*)(Bm + i);
        float4 c = *(const float4*)(Bm + i + 4);
        union { unsigned short u[8]; int4 v; } p;
        p.u[0] = f2bf(a.x); p.u[1] = f2bf(a.y); p.u[2] = f2bf(a.z); p.u[3] = f2bf(a.w);
        p.u[4] = f2bf(c.x); p.u[5] = f2bf(c.y); p.u[6] = f2bf(c.z); p.u[7] = f2bf(c.w);
        *(int4*)(Bb + i) = p.v;
    } else {
        const size_t i = ((size_t)(b - 192) * 256 + t) * 8;
        float4 a = *(const float4*)(x + i);
        float4 c = *(const float4*)(x + i + 4);
        union { unsigned short u[8]; int4 v; } p;
        p.u[0] = f2bf(a.x); p.u[1] = f2bf(a.y); p.u[2] = f2bf(a.z); p.u[3] = f2bf(a.w);
        p.u[4] = f2bf(c.x); p.u[5] = f2bf(c.y); p.u[6] = f2bf(c.z); p.u[7] = f2bf(c.w);
        *(int4*)(Xb + i) = p.v;
    }
}

// ---------------------------------------------------------------------------
// lora_weff: Weff[o][i] = nf4[nib]*absmax + sum_r B[o][r]*A[r][i]   (bf16 out)
// 128x128 tile, K=64 via two BK=32 steps (round-2 verified structure).
// Epilogue: absmax preloaded in LDS; adjacent-col pair packing via shfl_xor
// -> dword stores (half the store/load instructions).
// ---------------------------------------------------------------------------
#define BM 128
#define BN 128

__global__ __launch_bounds__(256) void lora_weff(
    const short* __restrict__ Bb,      // OUT_F x 64 bf16
    const short* __restrict__ At,      // IN_F x 64 bf16
    const int*   __restrict__ qw,      // int32 per byte, 2 nibbles
    const float* __restrict__ absmax,
    short*       __restrict__ W)       // OUT_F x IN_F bf16
{
    __shared__ short As[BM * 32];
    __shared__ short Bs[BN * 32];
    __shared__ float nf4s[16];
    __shared__ float amS[256];

    const int tid  = threadIdx.x;
    const int lane = tid & 63;
    const int wave = tid >> 6;
    const int bn = blockIdx.x * BN;   // i dim
    const int bm = blockIdx.y * BM;   // o dim

    if (tid < 16) nf4s[tid] = NF4_TAB[tid];
    // absmax for o in [bm,bm+128), both i-blocks (bn>>6) and (bn>>6)+1
    amS[tid] = absmax[(size_t)(bm + (tid & 127)) * 64 + (bn >> 6) + (tid >> 7)];

    const int ar = tid >> 2;
    const int ac = ((tid & 3) ^ ((ar >> 1) & 3)) * 8;
    const short* gA0 = Bb + (size_t)(bm + ar) * 64 + ac;
    const short* gA1 = gA0 + (size_t)64 * 64;
    const short* gB0 = At + (size_t)(bn + ar) * 64 + ac;
    const short* gB1 = gB0 + (size_t)64 * 64;
    short* lA0 = As + tid * 8;
    short* lA1 = As + 2048 + tid * 8;
    short* lB0 = Bs + tid * 8;
    short* lB1 = Bs + 2048 + tid * 8;

    const int wm = (wave >> 1) * 64;
    const int wn = (wave & 1) * 64;
    const int fr = lane & 15;
    const int fk_sw = (((lane >> 4) ^ ((fr >> 1) & 3))) * 8;

    floatx4 zero = {0.f, 0.f, 0.f, 0.f};
    floatx4 acc[4][4];
    #pragma unroll
    for (int i = 0; i < 4; ++i)
        #pragma unroll
        for (int j = 0; j < 4; ++j) acc[i][j] = zero;

    #pragma unroll
    for (int kt = 0; kt < 2; ++kt) {
        gll16(gA0, lA0);
        gll16(gA1, lA1);
        gll16(gB0, lB0);
        gll16(gB1, lB1);
        gA0 += 32; gA1 += 32; gB0 += 32; gB1 += 32;
        __syncthreads();

        shortx8 af[4], bfr[4];
        #pragma unroll
        for (int i = 0; i < 4; ++i) {
            af[i]  = *(const shortx8*)&As[(wm + i * 16 + fr) * 32 + fk_sw];
            bfr[i] = *(const shortx8*)&Bs[(wn + i * 16 + fr) * 32 + fk_sw];
        }
        #pragma unroll
        for (int i = 0; i < 4; ++i)
            #pragma unroll
            for (int j = 0; j < 4; ++j)
                acc[i][j] = __builtin_amdgcn_mfma_f32_16x16x32_bf16(
                    af[i], bfr[j], acc[i][j], 0, 0, 0);
        __syncthreads();
    }

    // epilogue
    const int row0  = bm + wm + (lane >> 4) * 4;
    const int col0  = bn + wn + fr;
    const int amsel = (wn >> 6) * 128;
    #pragma unroll
    for (int i = 0; i < 4; ++i) {
        #pragma unroll
        for (int rr = 0; rr < 4; ++rr) {
            const int o = row0 + i * 16 + rr;
            const float am = amS[amsel + (o - bm)];
            #pragma unroll
            for (int j = 0; j < 4; ++j) {
                const int ic = col0 + j * 16;
                const size_t flat = (size_t)o * IN_F + ic;
                const int q = qw[flat >> 1];               // same dword for lane pair
                const int nib = (fr & 1) ? ((q >> 4) & 15) : (q & 15);
                const unsigned v = f2bf(fmaf(nf4s[nib], am, acc[i][j][rr]));
                const unsigned hi = (unsigned)__shfl_xor((int)v, 1, 64);
                if (!(fr & 1))
                    *(unsigned*)(W + flat) = v | (hi << 16);
            }
        }
    }
}

// ---------------------------------------------------------------------------
// gemm_bt: C[M][N] = Xb[M][K] * Wb[N][K]^T
// 128x128 tile, BK=64 (half the barrier drains of BK=32), XOR-swizzled LDS:
// row r (128B) holds global chunk c at position c ^ (r&7)  -> <=2-way banks.
// ---------------------------------------------------------------------------
#define BK 64

__global__ __launch_bounds__(256) void gemm_bt(
    const short* __restrict__ Xb,   // M x K bf16
    const short* __restrict__ Wb,   // N x K bf16
    float*       __restrict__ C)    // M x N fp32
{
    __shared__ short As[BM * BK];   // 16 KB
    __shared__ short Bs[BN * BK];   // 16 KB

    const int tid  = threadIdx.x;
    const int lane = tid & 63;
    const int wave = tid >> 6;
    const int bn = blockIdx.x * BN;
    const int bm = blockIdx.y * BM;

    // staging: thread t -> LDS row (t>>3)+r*32, pos t&7; global chunk pos^ (row&7)
    const int ar  = tid >> 3;              // 0..31
    const int gc  = (tid & 7) ^ (ar & 7);  // swizzled global chunk
    const short* gA = Xb + (size_t)(bm + ar) * GK + gc * 8;
    const short* gB = Wb + (size_t)(bn + ar) * GK + gc * 8;
    short* lA = As + tid * 8;
    short* lB = Bs + tid * 8;

    const int wm = (wave >> 1) * 64;
    const int wn = (wave & 1) * 64;
    const int fr = lane & 15;
    const int qd = lane >> 4;              // 0..3
    const int rsw = fr & 7;                // row-bits for read-side swizzle

    floatx4 zero = {0.f, 0.f, 0.f, 0.f};
    floatx4 acc[4][4];
    #pragma unroll
    for (int i = 0; i < 4; ++i)
        #pragma unroll
        for (int j = 0; j < 4; ++j) acc[i][j] = zero;

    for (int kt = 0; kt < GK / BK; ++kt) {
        #pragma unroll
        for (int r = 0; r < 4; ++r) {
            gll16(gA + (size_t)r * 32 * GK, lA + r * 2048);
            gll16(gB + (size_t)r * 32 * GK, lB + r * 2048);
        }
        gA += BK; gB += BK;
        __syncthreads();

        #pragma unroll
        for (int ks = 0; ks < 2; ++ks) {
            const int p = ((ks * 4 + qd) ^ rsw) * 8;   // swizzled chunk pos
            shortx8 af[4], bfr[4];
            #pragma unroll
            for (int i = 0; i < 4; ++i) {
                af[i]  = *(const shortx8*)&As[(wm + i * 16 + fr) * BK + p];
                bfr[i] = *(const shortx8*)&Bs[(wn + i * 16 + fr) * BK + p];
            }
            #pragma unroll
            for (int i = 0; i < 4; ++i)
                #pragma unroll
                for (int j = 0; j < 4; ++j)
                    acc[i][j] = __builtin_amdgcn_mfma_f32_16x16x32_bf16(
                        af[i], bfr[j], acc[i][j], 0, 0, 0);
        }
        __syncthreads();
    }

    // epilogue: C/D layout col=lane&15, row=(lane>>4)*4+reg
    const int row0 = bm + wm + qd * 4;
    const int col0 = bn + wn + fr;
    #pragma unroll
    for (int i = 0; i < 4; ++i)
        #pragma unroll
        for (int j = 0; j < 4; ++j) {
            float* cp = C + (size_t)(row0 + i * 16) * OUT_F + col0 + j * 16;
            #pragma unroll
            for (int rr = 0; rr < 4; ++rr)
                cp[(size_t)rr * OUT_F] = acc[i][j][rr];
        }
}

// ---------------------------------------------------------------------------
extern "C" void kernel_launch(void* const* d_in, const int* in_sizes, int n_in,
                              void* d_out, int out_size, void* d_ws, size_t ws_size,
                              hipStream_t stream) {
    const float* x  = (const float*)d_in[0];
    const int*   qw = (const int*)d_in[1];
    const float* am = (const float*)d_in[2];
    const float* lA = (const float*)d_in[3];
    const float* lB = (const float*)d_in[4];
    float* out = (float*)d_out;

    short* Weff = (short*)d_ws;                                     // 32 MiB
    short* Xb   = (short*)((char*)d_ws + (size_t)OUT_F * IN_F * 2); // 64 MiB
    short* At   = (short*)((char*)d_ws + (size_t)(OUT_F * IN_F + M_ROWS * IN_F) * 2);
    short* Bb   = At + (size_t)IN_F * 64;   // At/Bb: 2 x 512 KiB past Xb

    prep<<<192 + (M_ROWS * IN_F) / 2048, 256, 0, stream>>>(lA, lB, x, At, Bb, Xb);
    lora_weff<<<dim3(IN_F / 128, OUT_F / 128), 256, 0, stream>>>(Bb, At, qw, am, Weff);
    gemm_bt<<<dim3(OUT_F / BN, M_ROWS / BM), 256, 0, stream>>>(Xb, Weff, out);
}